// Round 1
// baseline (749.784 us; speedup 1.0000x reference)
//
#include <hip/hip_runtime.h>

#define C_ 256
#define T_ 16
#define H_ 64
#define W_ 64
#define PT 5
#define PH 8
#define PW 8
#define OT 4
#define OH 7
#define OW 7
#define SSCALE (1.0f/16.0f)
#define TSCALE 1.0f

// ---------------- transpose (B,C,T,H,W) -> (B,T,H,W,C) ----------------
__global__ __launch_bounds__(256) void transpose_kernel(const float* __restrict__ f,
                                                        float* __restrict__ ft) {
    __shared__ float tile[32][33];
    const int THW = T_ * H_ * W_;
    int thw0 = blockIdx.x * 32;
    int c0 = blockIdx.y * 32;
    int b = blockIdx.z;
    int tx = threadIdx.x & 31;
    int ty = threadIdx.x >> 5;
#pragma unroll
    for (int k = 0; k < 4; ++k) {
        int c = c0 + ty + k * 8;
        tile[ty + k * 8][tx] = f[((size_t)b * C_ + c) * THW + thw0 + tx];
    }
    __syncthreads();
#pragma unroll
    for (int k = 0; k < 4; ++k) {
        int row = ty + k * 8;
        ft[((size_t)b * THW + thw0 + row) * C_ + c0 + tx] = tile[tx][row];
    }
}

// ---------------- main: one block per (roi, 32-channel group) ----------------
__global__ __launch_bounds__(256) void roi_kernel(const float* __restrict__ ft,
                                                  const float* __restrict__ rois,
                                                  float* __restrict__ out) {
    __shared__ float smp[PT * PH * PW][33];  // 320 x 33 floats, padded
    __shared__ float sroi[7];
    __shared__ int s_lo[21], s_hi[21];
    __shared__ float s_fr[21], s_vd[21];

    int r = blockIdx.y;
    int c0 = blockIdx.x * 32;

    if (threadIdx.x < 7) sroi[threadIdx.x] = rois[r * 7 + threadIdx.x];
    __syncthreads();

    if (threadIdx.x < 21) {
        int i = threadIdx.x;
        float start, end, size;
        int j, n;
        if (i < 5) {
            j = i; n = PT;
            start = sroi[5] * TSCALE; end = sroi[6] * TSCALE; size = (float)T_;
        } else if (i < 13) {
            j = i - 5; n = PH;
            start = sroi[2] * SSCALE; end = sroi[4] * SSCALE; size = (float)H_;
        } else {
            j = i - 13; n = PW;
            start = sroi[1] * SSCALE; end = sroi[3] * SSCALE; size = (float)W_;
        }
        float length = fmaxf(end - start + 1.0f, 1.0f);
        float step = length / (float)(n - 1);
        float coord = start + step * (float)j;
        float valid = (coord >= 0.0f && coord < size) ? 1.0f : 0.0f;
        float lo = fminf(fmaxf(floorf(coord), 0.0f), size - 1.0f);
        float frac = coord - lo;
        int lo_i = (int)lo;
        int hi_i = min(lo_i + 1, (int)size - 1);
        s_lo[i] = lo_i;
        s_hi[i] = hi_i;
        s_fr[i] = frac;
        s_vd[i] = valid;
    }
    __syncthreads();

    int b = (int)sroi[0];
    int c = threadIdx.x & 31;
    int psub = threadIdx.x >> 5;
    const float* fb = ft + (size_t)b * ((size_t)T_ * H_ * W_ * C_) + (size_t)(c0 + c);

    // phase 2: 320 trilinear samples x 32 channels
    for (int it = 0; it < 40; ++it) {
        int p = it * 8 + psub;
        int ti = p >> 6;
        int yi = (p >> 3) & 7;
        int xi = p & 7;
        int tl = s_lo[ti], th = s_hi[ti];
        float ftf = s_fr[ti];
        int yl = s_lo[5 + yi], yh = s_hi[5 + yi];
        float fy = s_fr[5 + yi];
        int xl = s_lo[13 + xi], xh = s_hi[13 + xi];
        float fx = s_fr[13 + xi];
        float mask = s_vd[ti] * s_vd[5 + yi] * s_vd[13 + xi];

        size_t o_tl_yl = ((size_t)(tl * H_ + yl) * W_) * C_;
        size_t o_tl_yh = ((size_t)(tl * H_ + yh) * W_) * C_;
        size_t o_th_yl = ((size_t)(th * H_ + yl) * W_) * C_;
        size_t o_th_yh = ((size_t)(th * H_ + yh) * W_) * C_;
        size_t oxl = (size_t)xl * C_;
        size_t oxh = (size_t)xh * C_;

        float v000 = fb[o_tl_yl + oxl];
        float v001 = fb[o_tl_yl + oxh];
        float v010 = fb[o_tl_yh + oxl];
        float v011 = fb[o_tl_yh + oxh];
        float v100 = fb[o_th_yl + oxl];
        float v101 = fb[o_th_yl + oxh];
        float v110 = fb[o_th_yh + oxl];
        float v111 = fb[o_th_yh + oxh];

        float vx00 = v000 + fx * (v001 - v000);
        float vx01 = v010 + fx * (v011 - v010);
        float vx10 = v100 + fx * (v101 - v100);
        float vx11 = v110 + fx * (v111 - v110);
        float vy0 = vx00 + fy * (vx01 - vx00);
        float vy1 = vx10 + fy * (vx11 - vx10);
        float v = vy0 + ftf * (vy1 - vy0);
        smp[p][c] = v * mask;
    }
    __syncthreads();

    // phase 3: 2x2x2 avg pool, contiguous coalesced stores
    const int NOUT = 32 * OT * OH * OW;  // 6272
    float* outc = out + ((size_t)r * C_ + c0) * (OT * OH * OW);
    for (int ov = 0; ov < 25; ++ov) {
        int o = ov * 256 + threadIdx.x;
        if (o < NOUT) {
            int cc = o / 196;
            int pos = o - cc * 196;
            int t = pos / 49;
            int rem = pos - t * 49;
            int h = rem / 7;
            int w = rem - h * 7;
            float s = 0.0f;
#pragma unroll
            for (int dt = 0; dt < 2; ++dt)
#pragma unroll
                for (int dh = 0; dh < 2; ++dh)
#pragma unroll
                    for (int dw = 0; dw < 2; ++dw)
                        s += smp[(t + dt) * 64 + (h + dh) * 8 + (w + dw)][cc];
            outc[(size_t)cc * 196 + pos] = s * 0.125f;
        }
    }
}

// ---------------- fallback: direct gather, one thread per output ----------------
__device__ __forceinline__ void axis_sample(float start, float end, float size, int n,
                                            int j, int& lo_i, int& hi_i, float& frac,
                                            float& valid) {
    float length = fmaxf(end - start + 1.0f, 1.0f);
    float step = length / (float)(n - 1);
    float coord = start + step * (float)j;
    valid = (coord >= 0.0f && coord < size) ? 1.0f : 0.0f;
    float lo = fminf(fmaxf(floorf(coord), 0.0f), size - 1.0f);
    frac = coord - lo;
    lo_i = (int)lo;
    hi_i = min(lo_i + 1, (int)size - 1);
}

__global__ void roi_direct(const float* __restrict__ f, const float* __restrict__ rois,
                           float* __restrict__ out, long long total) {
    long long idx = (long long)blockIdx.x * 256 + threadIdx.x;
    if (idx >= total) return;
    int w = (int)(idx % OW);
    long long q = idx / OW;
    int h = (int)(q % OH);
    q /= OH;
    int t = (int)(q % OT);
    q /= OT;
    int c = (int)(q % C_);
    int r = (int)(q / C_);

    float rb = rois[r * 7 + 0];
    float x1 = rois[r * 7 + 1] * SSCALE;
    float y1 = rois[r * 7 + 2] * SSCALE;
    float x2 = rois[r * 7 + 3] * SSCALE;
    float y2 = rois[r * 7 + 4] * SSCALE;
    float t1 = rois[r * 7 + 5] * TSCALE;
    float t2 = rois[r * 7 + 6] * TSCALE;
    int b = (int)rb;
    const float* fc = f + ((size_t)b * C_ + c) * (T_ * H_ * W_);

    float acc = 0.0f;
    for (int dt = 0; dt < 2; ++dt) {
        int tlo, thi; float tf, tv;
        axis_sample(t1, t2, (float)T_, PT, t + dt, tlo, thi, tf, tv);
        for (int dh = 0; dh < 2; ++dh) {
            int ylo, yhi; float yf, yv;
            axis_sample(y1, y2, (float)H_, PH, h + dh, ylo, yhi, yf, yv);
            for (int dw = 0; dw < 2; ++dw) {
                int xlo, xhi; float xf, xv;
                axis_sample(x1, x2, (float)W_, PW, w + dw, xlo, xhi, xf, xv);
                float v000 = fc[(tlo * H_ + ylo) * W_ + xlo];
                float v001 = fc[(tlo * H_ + ylo) * W_ + xhi];
                float v010 = fc[(tlo * H_ + yhi) * W_ + xlo];
                float v011 = fc[(tlo * H_ + yhi) * W_ + xhi];
                float v100 = fc[(thi * H_ + ylo) * W_ + xlo];
                float v101 = fc[(thi * H_ + ylo) * W_ + xhi];
                float v110 = fc[(thi * H_ + yhi) * W_ + xlo];
                float v111 = fc[(thi * H_ + yhi) * W_ + xhi];
                float vx00 = v000 + xf * (v001 - v000);
                float vx01 = v010 + xf * (v011 - v010);
                float vx10 = v100 + xf * (v101 - v100);
                float vx11 = v110 + xf * (v111 - v110);
                float vy0 = vx00 + yf * (vx01 - vx00);
                float vy1 = vx10 + yf * (vx11 - vx10);
                float v = vy0 + tf * (vy1 - vy0);
                acc += v * (tv * yv * xv);
            }
        }
    }
    out[idx] = acc * 0.125f;
}

extern "C" void kernel_launch(void* const* d_in, const int* in_sizes, int n_in,
                              void* d_out, int out_size, void* d_ws, size_t ws_size,
                              hipStream_t stream) {
    const float* feat = (const float*)d_in[0];
    const float* rois = (const float*)d_in[1];
    float* out = (float*)d_out;
    int nroi = in_sizes[1] / 7;
    int B = in_sizes[0] / (C_ * T_ * H_ * W_);
    size_t need = (size_t)B * T_ * H_ * W_ * C_ * sizeof(float);

    if (ws_size >= need) {
        dim3 g1(T_ * H_ * W_ / 32, C_ / 32, B);
        transpose_kernel<<<g1, 256, 0, stream>>>(feat, (float*)d_ws);
        dim3 g2(C_ / 32, nroi);
        roi_kernel<<<g2, 256, 0, stream>>>((const float*)d_ws, rois, out);
    } else {
        long long total = (long long)nroi * C_ * OT * OH * OW;
        roi_direct<<<(int)((total + 255) / 256), 256, 0, stream>>>(feat, rois, out, total);
    }
}